// Round 5
// baseline (101.250 us; speedup 1.0000x reference)
//
#include <hip/hip_runtime.h>
#include <hip/hip_bf16.h>

// HalfKP input layer, king-grouped + channel-split:
//   out[b,c] = bias[c] + sum_s [ sum_f p[b,f]*W[k_s,f,c] + W[k_s,640,c] ]
// B=1024, K=64, F=640, C=256.  W is (64, 641, 256) fp32 = 42 MB.
//
// R5 vs R4: fix occupancy (11% -> target 30-45%) without losing weight reuse.
//  - pack_masks: pieces (2.6 MB int32) -> 80 KB of u64 bitmasks, once.
//  - build_lists: per-king entry lists (atomics; order only selects which
//    block computes an entry, never the summation order -> deterministic).
//  - halfkp_group: grid (64 kings, 4 chunks of 16, 4 channel-quarters) =
//    1024 blocks (~640 busy, every CU covered). Block: 256 thr (4 waves),
//    lane = 1 channel. LDS-built 16-bit row-activity mask (row 640 forced
//    active), waves stride rows by 4, predicated adds into acc[16] (static
//    indices), 2-round LDS tree reduce, write per-entry channel slice.
//  - finalize: out = bias + partial[persp0] + partial[persp1].

#define F_DIM 640
#define C_DIM 256
#define SLAB_STRIDE (641 * 256)   // floats per king slab
#define NKING 64
#define CH 16                     // entries per chunk
#define MAXCH 4                   // chunk blocks per king
#define NCQ 4                     // channel quarters
#define LCAP 256                  // list capacity per king

// ws layout (bytes)
#define WS_CNT_OFF 0                         // 64*4
#define WS_LIST_OFF 1024                     // 64*256*4 = 64 KB
#define WS_MASK_OFF 66560                    // 1024*10*8 = 80 KB
#define WS_PART_OFF 148480                   // 2*1024*256*4 = 2 MB
#define WS_NEED (WS_PART_OFF + 2 * 1024 * 256 * 4)

__global__ __launch_bounds__(256)
void pack_masks(const int* __restrict__ pieces,          // (B,640) int32 0/1
                unsigned long long* __restrict__ mask,   // (B,10)
                int nwords)                              // B*10
{
    const int gw = blockIdx.x * 4 + (threadIdx.x >> 6);  // (b*10 + w)
    const int lane = threadIdx.x & 63;
    if (gw >= nwords) return;
    const int v = pieces[(size_t)gw * 64 + lane];        // == pieces[b*640 + w*64 + lane]
    const unsigned long long m = __ballot(v != 0);
    if (lane == 0) mask[gw] = m;
}

__global__ __launch_bounds__(256)
void build_lists(const int* __restrict__ kings, int* __restrict__ cnt,
                 int* __restrict__ list, int nent)
{
    const int id = blockIdx.x * 256 + threadIdx.x;   // entry id = b*2 + persp
    if (id >= nent) return;
    const int b = id >> 1, p = id & 1;
    const int k = kings[2 * b + p];
    const int pos = atomicAdd(&cnt[k], 1);
    if (pos < LCAP) list[k * LCAP + pos] = id;
}

__global__ __launch_bounds__(256)
void halfkp_group(const float* __restrict__ W,                 // (64,641,256)
                  const unsigned long long* __restrict__ mask, // (B,10)
                  const int* __restrict__ cnt,
                  const int* __restrict__ list,
                  float* __restrict__ partial)                 // (2,B,256)
{
    const int k  = blockIdx.x;
    const int ci = blockIdx.y;
    const int cq = blockIdx.z;
    const int t  = threadIdx.x;
    const int wv = t >> 6;
    const int lane = t & 63;
    const int c = cq * 64 + lane;

    __shared__ int s_ent[CH];
    __shared__ unsigned long long s_m64[CH][10];
    __shared__ unsigned short s_m16[F_DIM + 1];
    __shared__ float s_red[2][CH][64];                  // 8 KB

    const int n_k = min(cnt[k], LCAP);
    const float* __restrict__ Wf = W + (size_t)k * SLAB_STRIDE + c;

    for (int base0 = 0; base0 < n_k; base0 += MAXCH * CH) {
        const int base = base0 + ci * CH;
        const int nc = min(n_k - base, CH);
        if (nc <= 0) continue;                           // block-uniform

        if (t < CH) s_ent[t] = (t < nc) ? list[k * LCAP + base + t] : -1;
        __syncthreads();

        for (int i = t; i < CH * 10; i += 256) {
            const int e = i / 10, w = i - e * 10;
            const int id = s_ent[e];
            s_m64[e][w] = (id >= 0) ? mask[(size_t)(id >> 1) * 10 + w] : 0ull;
        }
        __syncthreads();

        for (int f = t; f <= F_DIM; f += 256) {
            unsigned m;
            if (f == F_DIM) {
                m = (1u << nc) - 1u;                     // row 640 always active
            } else {
                const int w = f >> 6, bit = f & 63;
                m = 0;
                #pragma unroll
                for (int e = 0; e < CH; ++e)
                    m |= (unsigned)((s_m64[e][w] >> bit) & 1ull) << e;
            }
            s_m16[f] = (unsigned short)m;
        }
        __syncthreads();

        float acc[CH];
        #pragma unroll
        for (int e = 0; e < CH; ++e) acc[e] = 0.f;

        // Wave wv covers rows f ≡ wv (mod 4); lane = one channel.
        for (int fr = wv; fr <= F_DIM; fr += 4) {
            const unsigned m = __builtin_amdgcn_readfirstlane((unsigned)s_m16[fr]);
            if (m == 0u) continue;
            const float w4 = Wf[(size_t)fr * C_DIM];
            #pragma unroll
            for (int e = 0; e < CH; ++e)
                if (m & (1u << e)) acc[e] += w4;
        }

        // 2-round deterministic tree reduce: 4 -> 2 -> 1 waves.
        __syncthreads();
        if (wv >= 2) {
            #pragma unroll
            for (int e = 0; e < CH; ++e) s_red[wv - 2][e][lane] = acc[e];
        }
        __syncthreads();
        if (wv < 2) {
            #pragma unroll
            for (int e = 0; e < CH; ++e) acc[e] += s_red[wv][e][lane];
        }
        __syncthreads();
        if (wv == 1) {
            #pragma unroll
            for (int e = 0; e < CH; ++e) s_red[0][e][lane] = acc[e];
        }
        __syncthreads();
        if (wv == 0) {
            #pragma unroll
            for (int e = 0; e < CH; ++e) acc[e] += s_red[0][e][lane];
            for (int e = 0; e < CH; ++e) {
                if (e < nc) {
                    const int id = s_ent[e];
                    const int b = id >> 1, p = id & 1;
                    partial[((size_t)p * 1024 + b) * C_DIM + c] = acc[e];
                }
            }
        }
        __syncthreads();   // protect LDS before next sweep
    }
}

__global__ __launch_bounds__(256)
void finalize(const float* __restrict__ partial,
              const float* __restrict__ bias,
              float* __restrict__ out)
{
    const int i = blockIdx.x * 256 + threadIdx.x;    // float4 index, B*64 total
    const float4 b4 = ((const float4*)bias)[i & 63];
    const float4 p0 = ((const float4*)partial)[i];
    const float4 p1 = ((const float4*)partial)[1024 * 64 + i];
    float4 o;
    o.x = b4.x + p0.x + p1.x;
    o.y = b4.y + p0.y + p1.y;
    o.z = b4.z + p0.z + p1.z;
    o.w = b4.w + p0.w + p1.w;
    ((float4*)out)[i] = o;
}

// ---- fallback (R3 path) if ws is too small ----
__global__ __launch_bounds__(256)
void halfkp_fallback(const int* __restrict__ pieces, const int* __restrict__ kings,
                     const float* __restrict__ W, const float* __restrict__ bias,
                     float* __restrict__ out)
{
    const int b = blockIdx.x;
    const int c = threadIdx.x;
    const int lane = c & 63;
    const int k0 = kings[2 * b + 0];
    const int k1 = kings[2 * b + 1];
    const float* W0 = W + (size_t)k0 * SLAB_STRIDE + c;
    const float* W1 = W + (size_t)k1 * SLAB_STRIDE + c;
    float acc = bias[c] + W0[640 * 256] + W1[640 * 256];
    const int* pi = pieces + (size_t)b * F_DIM;
    #pragma unroll
    for (int ch = 0; ch < 10; ++ch) {
        int v = pi[ch * 64 + lane];
        unsigned long long m = __ballot(v != 0);
        const float* b0 = W0 + ch * 64 * 256;
        const float* b1 = W1 + ch * 64 * 256;
        while (m) {
            const int f = __builtin_ctzll(m);
            m &= m - 1;
            acc += b0[f * 256] + b1[f * 256];
        }
    }
    out[(size_t)b * C_DIM + c] = acc;
}

extern "C" void kernel_launch(void* const* d_in, const int* in_sizes, int n_in,
                              void* d_out, int out_size, void* d_ws, size_t ws_size,
                              hipStream_t stream) {
    const int* pieces = (const int*)d_in[0];   // (1024, 640) int32 bools
    const int* kings  = (const int*)d_in[1];   // (1024, 2) int32
    const float* W    = (const float*)d_in[2]; // (64, 641, 256) f32
    const float* bias = (const float*)d_in[3]; // (256,) f32
    float* out        = (float*)d_out;         // (1024, 256) f32

    const int B = in_sizes[1] / 2;             // 1024
    const int nent = 2 * B;

    if (ws_size < (size_t)WS_NEED) {
        halfkp_fallback<<<dim3(B), dim3(C_DIM), 0, stream>>>(pieces, kings, W, bias, out);
        return;
    }

    int* cnt  = (int*)((char*)d_ws + WS_CNT_OFF);
    int* list = (int*)((char*)d_ws + WS_LIST_OFF);
    unsigned long long* mask = (unsigned long long*)((char*)d_ws + WS_MASK_OFF);
    float* part = (float*)((char*)d_ws + WS_PART_OFF);

    const int nwords = B * 10;

    hipMemsetAsync(cnt, 0, NKING * sizeof(int), stream);
    pack_masks<<<dim3((nwords + 3) / 4), dim3(256), 0, stream>>>(pieces, mask, nwords);
    build_lists<<<dim3((nent + 255) / 256), dim3(256), 0, stream>>>(kings, cnt, list, nent);
    halfkp_group<<<dim3(NKING, MAXCH, NCQ), dim3(256), 0, stream>>>(W, mask, cnt, list, part);
    finalize<<<dim3(B * 64 / 256), dim3(256), 0, stream>>>(part, bias, out);
}

// Round 6
// 84.207 us; speedup vs baseline: 1.2024x; 1.2024x over previous
//
#include <hip/hip_runtime.h>
#include <hip/hip_bf16.h>

// HalfKP input layer, king-grouped + channel-split, BRANCHLESS inner loop:
//   out[b,c] = bias[c] + sum_s [ sum_f p[b,f]*W[k_s,f,c] + W[k_s,640,c] ]
// B=1024, K=64, F=640, C=256.  W is (64, 641, 256) fp32 = 42 MB.
//
// R6 vs R5: R5 was scalar-branch-bound (16 s_cbranch per weight row; VALUBusy
// 21%, BW 2.5%, occupancy 25% -> nothing saturated). Replace predicated adds
// with dense fmaf(bit, w, acc): bit = s_and + s_cselect (SALU, branchless),
// fmac pipelines fully; 2-row unroll for load ILP. Bit-identical math to R5.

#define F_DIM 640
#define C_DIM 256
#define SLAB_STRIDE (641 * 256)   // floats per king slab
#define NKING 64
#define CH 16                     // entries per chunk
#define MAXCH 4                   // chunk blocks per king
#define NCQ 4                     // channel quarters
#define LCAP 256                  // list capacity per king

// ws layout (bytes)
#define WS_CNT_OFF 0                         // 64*4
#define WS_LIST_OFF 1024                     // 64*256*4 = 64 KB
#define WS_MASK_OFF 66560                    // 1024*10*8 = 80 KB
#define WS_PART_OFF 148480                   // 2*1024*256*4 = 2 MB
#define WS_NEED (WS_PART_OFF + 2 * 1024 * 256 * 4)

__global__ __launch_bounds__(256)
void pack_masks(const int* __restrict__ pieces,          // (B,640) int32 0/1
                unsigned long long* __restrict__ mask,   // (B,10)
                int nwords)                              // B*10
{
    const int gw = blockIdx.x * 4 + (threadIdx.x >> 6);  // (b*10 + w)
    const int lane = threadIdx.x & 63;
    if (gw >= nwords) return;
    const int v = pieces[(size_t)gw * 64 + lane];
    const unsigned long long m = __ballot(v != 0);
    if (lane == 0) mask[gw] = m;
}

__global__ __launch_bounds__(256)
void build_lists(const int* __restrict__ kings, int* __restrict__ cnt,
                 int* __restrict__ list, int nent)
{
    const int id = blockIdx.x * 256 + threadIdx.x;   // entry id = b*2 + persp
    if (id >= nent) return;
    const int b = id >> 1, p = id & 1;
    const int k = kings[2 * b + p];
    const int pos = atomicAdd(&cnt[k], 1);
    if (pos < LCAP) list[k * LCAP + pos] = id;
}

__global__ __launch_bounds__(256)
void halfkp_group(const float* __restrict__ W,                 // (64,641,256)
                  const unsigned long long* __restrict__ mask, // (B,10)
                  const int* __restrict__ cnt,
                  const int* __restrict__ list,
                  float* __restrict__ partial)                 // (2,B,256)
{
    const int k  = blockIdx.x;
    const int ci = blockIdx.y;
    const int cq = blockIdx.z;
    const int t  = threadIdx.x;
    const int wv = t >> 6;
    const int lane = t & 63;
    const int c = cq * 64 + lane;

    __shared__ int s_ent[CH];
    __shared__ unsigned long long s_m64[CH][10];
    __shared__ unsigned short s_m16[F_DIM + 1];
    __shared__ float s_red[2][CH][64];                  // 8 KB

    const int n_k = min(cnt[k], LCAP);
    const float* __restrict__ Wf = W + (size_t)k * SLAB_STRIDE + c;

    for (int base0 = 0; base0 < n_k; base0 += MAXCH * CH) {
        const int base = base0 + ci * CH;
        const int nc = min(n_k - base, CH);
        if (nc <= 0) continue;                           // block-uniform

        if (t < CH) s_ent[t] = (t < nc) ? list[k * LCAP + base + t] : -1;
        __syncthreads();

        for (int i = t; i < CH * 10; i += 256) {
            const int e = i / 10, w = i - e * 10;
            const int id = s_ent[e];
            s_m64[e][w] = (id >= 0) ? mask[(size_t)(id >> 1) * 10 + w] : 0ull;
        }
        __syncthreads();

        for (int f = t; f <= F_DIM; f += 256) {
            unsigned m;
            if (f == F_DIM) {
                m = (1u << nc) - 1u;                     // row 640 always active
            } else {
                const int w = f >> 6, bit = f & 63;
                m = 0;
                #pragma unroll
                for (int e = 0; e < CH; ++e)
                    m |= (unsigned)((s_m64[e][w] >> bit) & 1ull) << e;
            }
            s_m16[f] = (unsigned short)m;
        }
        __syncthreads();

        float acc[CH];
        #pragma unroll
        for (int e = 0; e < CH; ++e) acc[e] = 0.f;

        // Wave wv covers rows f ≡ wv (mod 4). Branchless dense fmac:
        // bit = s_cselect(1.0, 0.0), acc[e] = fmaf(bit, w, acc[e]).
        // 2-row unroll -> 2 independent 256B row loads in flight.
        int fr = wv;
        for (; fr + 4 <= F_DIM; fr += 8) {
            const unsigned m0 = __builtin_amdgcn_readfirstlane((unsigned)s_m16[fr]);
            const unsigned m1 = __builtin_amdgcn_readfirstlane((unsigned)s_m16[fr + 4]);
            const float w0 = Wf[(size_t)fr * C_DIM];
            const float w1 = Wf[(size_t)(fr + 4) * C_DIM];
            #pragma unroll
            for (int e = 0; e < CH; ++e) {
                const float b0 = (m0 & (1u << e)) ? 1.0f : 0.0f;
                acc[e] = fmaf(b0, w0, acc[e]);
            }
            #pragma unroll
            for (int e = 0; e < CH; ++e) {
                const float b1 = (m1 & (1u << e)) ? 1.0f : 0.0f;
                acc[e] = fmaf(b1, w1, acc[e]);
            }
        }
        for (; fr <= F_DIM; fr += 4) {
            const unsigned m0 = __builtin_amdgcn_readfirstlane((unsigned)s_m16[fr]);
            const float w0 = Wf[(size_t)fr * C_DIM];
            #pragma unroll
            for (int e = 0; e < CH; ++e) {
                const float b0 = (m0 & (1u << e)) ? 1.0f : 0.0f;
                acc[e] = fmaf(b0, w0, acc[e]);
            }
        }

        // 2-round deterministic tree reduce: 4 -> 2 -> 1 waves.
        __syncthreads();
        if (wv >= 2) {
            #pragma unroll
            for (int e = 0; e < CH; ++e) s_red[wv - 2][e][lane] = acc[e];
        }
        __syncthreads();
        if (wv < 2) {
            #pragma unroll
            for (int e = 0; e < CH; ++e) acc[e] += s_red[wv][e][lane];
        }
        __syncthreads();
        if (wv == 1) {
            #pragma unroll
            for (int e = 0; e < CH; ++e) s_red[0][e][lane] = acc[e];
        }
        __syncthreads();
        if (wv == 0) {
            #pragma unroll
            for (int e = 0; e < CH; ++e) acc[e] += s_red[0][e][lane];
            for (int e = 0; e < CH; ++e) {
                if (e < nc) {
                    const int id = s_ent[e];
                    const int b = id >> 1, p = id & 1;
                    partial[((size_t)p * 1024 + b) * C_DIM + c] = acc[e];
                }
            }
        }
        __syncthreads();   // protect LDS before next sweep
    }
}

__global__ __launch_bounds__(256)
void finalize(const float* __restrict__ partial,
              const float* __restrict__ bias,
              float* __restrict__ out)
{
    const int i = blockIdx.x * 256 + threadIdx.x;    // float4 index, B*64 total
    const float4 b4 = ((const float4*)bias)[i & 63];
    const float4 p0 = ((const float4*)partial)[i];
    const float4 p1 = ((const float4*)partial)[1024 * 64 + i];
    float4 o;
    o.x = b4.x + p0.x + p1.x;
    o.y = b4.y + p0.y + p1.y;
    o.z = b4.z + p0.z + p1.z;
    o.w = b4.w + p0.w + p1.w;
    ((float4*)out)[i] = o;
}

// ---- fallback (R3 path) if ws is too small ----
__global__ __launch_bounds__(256)
void halfkp_fallback(const int* __restrict__ pieces, const int* __restrict__ kings,
                     const float* __restrict__ W, const float* __restrict__ bias,
                     float* __restrict__ out)
{
    const int b = blockIdx.x;
    const int c = threadIdx.x;
    const int lane = c & 63;
    const int k0 = kings[2 * b + 0];
    const int k1 = kings[2 * b + 1];
    const float* W0 = W + (size_t)k0 * SLAB_STRIDE + c;
    const float* W1 = W + (size_t)k1 * SLAB_STRIDE + c;
    float acc = bias[c] + W0[640 * 256] + W1[640 * 256];
    const int* pi = pieces + (size_t)b * F_DIM;
    #pragma unroll
    for (int ch = 0; ch < 10; ++ch) {
        int v = pi[ch * 64 + lane];
        unsigned long long m = __ballot(v != 0);
        const float* b0 = W0 + ch * 64 * 256;
        const float* b1 = W1 + ch * 64 * 256;
        while (m) {
            const int f = __builtin_ctzll(m);
            m &= m - 1;
            acc += b0[f * 256] + b1[f * 256];
        }
    }
    out[(size_t)b * C_DIM + c] = acc;
}

extern "C" void kernel_launch(void* const* d_in, const int* in_sizes, int n_in,
                              void* d_out, int out_size, void* d_ws, size_t ws_size,
                              hipStream_t stream) {
    const int* pieces = (const int*)d_in[0];   // (1024, 640) int32 bools
    const int* kings  = (const int*)d_in[1];   // (1024, 2) int32
    const float* W    = (const float*)d_in[2]; // (64, 641, 256) f32
    const float* bias = (const float*)d_in[3]; // (256,) f32
    float* out        = (float*)d_out;         // (1024, 256) f32

    const int B = in_sizes[1] / 2;             // 1024
    const int nent = 2 * B;

    if (ws_size < (size_t)WS_NEED) {
        halfkp_fallback<<<dim3(B), dim3(C_DIM), 0, stream>>>(pieces, kings, W, bias, out);
        return;
    }

    int* cnt  = (int*)((char*)d_ws + WS_CNT_OFF);
    int* list = (int*)((char*)d_ws + WS_LIST_OFF);
    unsigned long long* mask = (unsigned long long*)((char*)d_ws + WS_MASK_OFF);
    float* part = (float*)((char*)d_ws + WS_PART_OFF);

    const int nwords = B * 10;

    hipMemsetAsync(cnt, 0, NKING * sizeof(int), stream);
    pack_masks<<<dim3((nwords + 3) / 4), dim3(256), 0, stream>>>(pieces, mask, nwords);
    build_lists<<<dim3((nent + 255) / 256), dim3(256), 0, stream>>>(kings, cnt, list, nent);
    halfkp_group<<<dim3(NKING, MAXCH, NCQ), dim3(256), 0, stream>>>(W, mask, cnt, list, part);
    finalize<<<dim3(B * 64 / 256), dim3(256), 0, stream>>>(part, bias, out);
}

// Round 7
// 75.908 us; speedup vs baseline: 1.3339x; 1.1093x over previous
//
#include <hip/hip_runtime.h>
#include <hip/hip_bf16.h>

// HalfKP input layer, king-grouped + channel-split, deep-ILP inner loop:
//   out[b,c] = bias[c] + sum_s [ sum_f p[b,f]*W[k_s,f,c] + W[k_s,640,c] ]
// B=1024, K=64, F=640, C=256.  W is (64, 641, 256) fp32 = 42 MB.
//
// R7 vs R6: R6 was memory-LATENCY-bound (~1094 cyc/row measured vs 500-cyc
// L3 latency => loads serialized, 2 waves/SIMD, nothing saturated). Fix:
//  - 8-row register preload (8 global dwords in flight per wave),
//  - contiguous 80-row range per wave (L2 streaming),
//  - 8 waves/block (512 thr), 3-round LDS tree reduce -> ~20 waves/CU.
// Math is bit-identical per entry: rows ascend within each wave's fixed
// range; reduce tree order fixed; list order never affects summation order.

#define F_DIM 640
#define C_DIM 256
#define SLAB_STRIDE (641 * 256)   // floats per king slab
#define NKING 64
#define CH 16                     // entries per chunk
#define MAXCH 4                   // chunk blocks per king
#define NCQ 4                     // channel quarters
#define LCAP 256                  // list capacity per king

// ws layout (bytes)
#define WS_CNT_OFF 0                         // 64*4
#define WS_LIST_OFF 1024                     // 64*256*4 = 64 KB
#define WS_MASK_OFF 66560                    // 1024*10*8 = 80 KB
#define WS_PART_OFF 148480                   // 2*1024*256*4 = 2 MB
#define WS_NEED (WS_PART_OFF + 2 * 1024 * 256 * 4)

__global__ __launch_bounds__(256)
void pack_masks(const int* __restrict__ pieces,          // (B,640) int32 0/1
                unsigned long long* __restrict__ mask,   // (B,10)
                int nwords)                              // B*10
{
    const int gw = blockIdx.x * 4 + (threadIdx.x >> 6);  // (b*10 + w)
    const int lane = threadIdx.x & 63;
    if (gw >= nwords) return;
    const int v = pieces[(size_t)gw * 64 + lane];
    const unsigned long long m = __ballot(v != 0);
    if (lane == 0) mask[gw] = m;
}

__global__ __launch_bounds__(256)
void build_lists(const int* __restrict__ kings, int* __restrict__ cnt,
                 int* __restrict__ list, int nent)
{
    const int id = blockIdx.x * 256 + threadIdx.x;   // entry id = b*2 + persp
    if (id >= nent) return;
    const int b = id >> 1, p = id & 1;
    const int k = kings[2 * b + p];
    const int pos = atomicAdd(&cnt[k], 1);
    if (pos < LCAP) list[k * LCAP + pos] = id;
}

__global__ __launch_bounds__(512)
void halfkp_group(const float* __restrict__ W,                 // (64,641,256)
                  const unsigned long long* __restrict__ mask, // (B,10)
                  const int* __restrict__ cnt,
                  const int* __restrict__ list,
                  float* __restrict__ partial)                 // (2,B,256)
{
    const int k  = blockIdx.x;
    const int ci = blockIdx.y;
    const int cq = blockIdx.z;
    const int t  = threadIdx.x;
    const int wv = t >> 6;       // 0..7
    const int lane = t & 63;
    const int c = cq * 64 + lane;

    __shared__ int s_ent[CH];
    __shared__ unsigned long long s_m64[CH][10];
    __shared__ unsigned short s_m16[F_DIM + 1];
    __shared__ float s_red[4][CH][64];                  // 16 KB

    const int n_k = min(cnt[k], LCAP);
    const float* __restrict__ Wf = W + (size_t)k * SLAB_STRIDE + c;

    for (int base0 = 0; base0 < n_k; base0 += MAXCH * CH) {
        const int base = base0 + ci * CH;
        const int nc = min(n_k - base, CH);
        if (nc <= 0) continue;                           // block-uniform

        if (t < CH) s_ent[t] = (t < nc) ? list[k * LCAP + base + t] : -1;
        __syncthreads();

        for (int i = t; i < CH * 10; i += 512) {
            const int e = i / 10, w = i - e * 10;
            const int id = s_ent[e];
            s_m64[e][w] = (id >= 0) ? mask[(size_t)(id >> 1) * 10 + w] : 0ull;
        }
        __syncthreads();

        for (int f = t; f <= F_DIM; f += 512) {
            unsigned m;
            if (f == F_DIM) {
                m = (1u << nc) - 1u;                     // row 640 always active
            } else {
                const int w = f >> 6, bit = f & 63;
                m = 0;
                #pragma unroll
                for (int e = 0; e < CH; ++e)
                    m |= (unsigned)((s_m64[e][w] >> bit) & 1ull) << e;
            }
            s_m16[f] = (unsigned short)m;
        }
        __syncthreads();

        float acc[CH];
        #pragma unroll
        for (int e = 0; e < CH; ++e) acc[e] = 0.f;

        // Wave wv owns contiguous rows [wv*80, wv*80+80); wave 7 also row 640.
        // 8-row register preload: 8 independent global dwords + 8 mask reads
        // in flight, then 8*16 branchless fmacs (bit via s_and+s_cselect).
        const int r0 = wv * 80;
        #pragma unroll 1
        for (int g = 0; g < 80; g += 8) {
            float wreg[8];
            unsigned short mreg[8];
            #pragma unroll
            for (int j = 0; j < 8; ++j) {
                mreg[j] = s_m16[r0 + g + j];
                wreg[j] = Wf[(size_t)(r0 + g + j) * C_DIM];
            }
            #pragma unroll
            for (int j = 0; j < 8; ++j) {
                const unsigned m = __builtin_amdgcn_readfirstlane((unsigned)mreg[j]);
                #pragma unroll
                for (int e = 0; e < CH; ++e) {
                    const float b = (m & (1u << e)) ? 1.0f : 0.0f;
                    acc[e] = fmaf(b, wreg[j], acc[e]);
                }
            }
        }
        if (wv == 7) {
            const unsigned m = __builtin_amdgcn_readfirstlane((unsigned)s_m16[F_DIM]);
            const float w0 = Wf[(size_t)F_DIM * C_DIM];
            #pragma unroll
            for (int e = 0; e < CH; ++e) {
                const float b = (m & (1u << e)) ? 1.0f : 0.0f;
                acc[e] = fmaf(b, w0, acc[e]);
            }
        }

        // 3-round deterministic tree reduce: 8 -> 4 -> 2 -> 1 waves.
        __syncthreads();
        if (wv >= 4) {
            #pragma unroll
            for (int e = 0; e < CH; ++e) s_red[wv - 4][e][lane] = acc[e];
        }
        __syncthreads();
        if (wv < 4) {
            #pragma unroll
            for (int e = 0; e < CH; ++e) acc[e] += s_red[wv][e][lane];
        }
        __syncthreads();
        if (wv == 2 || wv == 3) {
            #pragma unroll
            for (int e = 0; e < CH; ++e) s_red[wv - 2][e][lane] = acc[e];
        }
        __syncthreads();
        if (wv < 2) {
            #pragma unroll
            for (int e = 0; e < CH; ++e) acc[e] += s_red[wv][e][lane];
        }
        __syncthreads();
        if (wv == 1) {
            #pragma unroll
            for (int e = 0; e < CH; ++e) s_red[0][e][lane] = acc[e];
        }
        __syncthreads();
        if (wv == 0) {
            #pragma unroll
            for (int e = 0; e < CH; ++e) acc[e] += s_red[0][e][lane];
            for (int e = 0; e < CH; ++e) {
                if (e < nc) {
                    const int id = s_ent[e];
                    const int b = id >> 1, p = id & 1;
                    partial[((size_t)p * 1024 + b) * C_DIM + c] = acc[e];
                }
            }
        }
        __syncthreads();   // protect LDS before next sweep
    }
}

__global__ __launch_bounds__(256)
void finalize(const float* __restrict__ partial,
              const float* __restrict__ bias,
              float* __restrict__ out)
{
    const int i = blockIdx.x * 256 + threadIdx.x;    // float4 index, B*64 total
    const float4 b4 = ((const float4*)bias)[i & 63];
    const float4 p0 = ((const float4*)partial)[i];
    const float4 p1 = ((const float4*)partial)[1024 * 64 + i];
    float4 o;
    o.x = b4.x + p0.x + p1.x;
    o.y = b4.y + p0.y + p1.y;
    o.z = b4.z + p0.z + p1.z;
    o.w = b4.w + p0.w + p1.w;
    ((float4*)out)[i] = o;
}

// ---- fallback (R3 path) if ws is too small ----
__global__ __launch_bounds__(256)
void halfkp_fallback(const int* __restrict__ pieces, const int* __restrict__ kings,
                     const float* __restrict__ W, const float* __restrict__ bias,
                     float* __restrict__ out)
{
    const int b = blockIdx.x;
    const int c = threadIdx.x;
    const int lane = c & 63;
    const int k0 = kings[2 * b + 0];
    const int k1 = kings[2 * b + 1];
    const float* W0 = W + (size_t)k0 * SLAB_STRIDE + c;
    const float* W1 = W + (size_t)k1 * SLAB_STRIDE + c;
    float acc = bias[c] + W0[640 * 256] + W1[640 * 256];
    const int* pi = pieces + (size_t)b * F_DIM;
    #pragma unroll
    for (int ch = 0; ch < 10; ++ch) {
        int v = pi[ch * 64 + lane];
        unsigned long long m = __ballot(v != 0);
        const float* b0 = W0 + ch * 64 * 256;
        const float* b1 = W1 + ch * 64 * 256;
        while (m) {
            const int f = __builtin_ctzll(m);
            m &= m - 1;
            acc += b0[f * 256] + b1[f * 256];
        }
    }
    out[(size_t)b * C_DIM + c] = acc;
}

extern "C" void kernel_launch(void* const* d_in, const int* in_sizes, int n_in,
                              void* d_out, int out_size, void* d_ws, size_t ws_size,
                              hipStream_t stream) {
    const int* pieces = (const int*)d_in[0];   // (1024, 640) int32 bools
    const int* kings  = (const int*)d_in[1];   // (1024, 2) int32
    const float* W    = (const float*)d_in[2]; // (64, 641, 256) f32
    const float* bias = (const float*)d_in[3]; // (256,) f32
    float* out        = (float*)d_out;         // (1024, 256) f32

    const int B = in_sizes[1] / 2;             // 1024
    const int nent = 2 * B;

    if (ws_size < (size_t)WS_NEED) {
        halfkp_fallback<<<dim3(B), dim3(C_DIM), 0, stream>>>(pieces, kings, W, bias, out);
        return;
    }

    int* cnt  = (int*)((char*)d_ws + WS_CNT_OFF);
    int* list = (int*)((char*)d_ws + WS_LIST_OFF);
    unsigned long long* mask = (unsigned long long*)((char*)d_ws + WS_MASK_OFF);
    float* part = (float*)((char*)d_ws + WS_PART_OFF);

    const int nwords = B * 10;

    hipMemsetAsync(cnt, 0, NKING * sizeof(int), stream);
    pack_masks<<<dim3((nwords + 3) / 4), dim3(256), 0, stream>>>(pieces, mask, nwords);
    build_lists<<<dim3((nent + 255) / 256), dim3(256), 0, stream>>>(kings, cnt, list, nent);
    halfkp_group<<<dim3(NKING, MAXCH, NCQ), dim3(512), 0, stream>>>(W, mask, cnt, list, part);
    finalize<<<dim3(B * 64 / 256), dim3(256), 0, stream>>>(part, bias, out);
}

// Round 8
// 34.438 us; speedup vs baseline: 2.9401x; 2.2042x over previous
//
#include <hip/hip_runtime.h>
#include <hip/hip_bf16.h>

// HalfKP input layer, king-grouped MFMA formulation:
//   per king k: D = A_k (64x672 bf16 0/1, entries as rows, padded) x W_k (672x256 -> bf16)
//   out[b,c] = bias[c] + D[entry(b,p0)] + D[entry(b,p1)]
// B=1024, K=64, F=640(+1 extra row), C=256. W is (64,641,256) fp32 = 42 MB.
//
// R8: R5-R7 showed the scalar-predicated formulation carries 2-3 overhead ops
// per useful fmac and plateaus at ~61us (VALUBusy 31%, nothing saturated).
// MFMA does bit-apply+accumulate in the matrix pipe. v_mfma_f32_16x16x16_bf16
// (inline asm; documented CDNA layout: A[r=l&15][k=4*(l>>4)+j], B[k][c=l&15],
// D: row=4*(l>>4)+reg, col=l&15 (m89-verified C/D rule)).
// Grid (64 kings, 4 c-quarters), 512 thr = 8 waves = 4 N-tiles x 2 K-halves.
// K-halves reduced via LDS in fixed order; bf16 cvt is RNE -> abs err ~0.1.

#define F_DIM 640
#define C_DIM 256
#define SLAB_STRIDE (641 * 256)   // floats per king slab
#define NKING 64
#define NCQ 4                     // channel quarters
#define LCAP 256                  // list capacity per king

// ws layout (bytes) — unchanged from R5-R7 (proven to fit)
#define WS_CNT_OFF 0                         // 64*4
#define WS_LIST_OFF 1024                     // 64*256*4 = 64 KB
#define WS_MASK_OFF 66560                    // 1024*10*8 = 80 KB
#define WS_PART_OFF 148480                   // 2*1024*256*4 = 2 MB
#define WS_NEED (WS_PART_OFF + 2 * 1024 * 256 * 4)

typedef float  f32x4 __attribute__((ext_vector_type(4)));
typedef short  s16x4 __attribute__((ext_vector_type(4)));

__device__ __forceinline__ unsigned f2bf_pk(float a, float b) {
    // two RNE fp32->bf16, packed low|high
    union { float f; unsigned u; } x, y;
    x.f = a; y.f = b;
    const unsigned ra = (x.u + 0x7FFFu + ((x.u >> 16) & 1u)) >> 16;
    const unsigned rb = (y.u + 0x7FFFu + ((y.u >> 16) & 1u)) >> 16;
    return (ra & 0xFFFFu) | (rb << 16);
}

__device__ __forceinline__ s16x4 mk_a(unsigned short m16, int g) {
    // A-frag for one 16x16x16 MFMA: 4 bf16 0/1 from nibble g of the k-window
    const unsigned n = ((unsigned)m16 >> (g * 4)) & 0xFu;
    union { unsigned u[2]; s16x4 v; } r;
    r.u[0] = ((n & 1u) ? 0x3F80u : 0u) | ((n & 2u) ? 0x3F800000u : 0u);
    r.u[1] = ((n & 4u) ? 0x3F80u : 0u) | ((n & 8u) ? 0x3F800000u : 0u);
    return r.v;
}

// fused: piece bitmask packing + per-king list build (atomic order only picks
// which A-row an entry occupies; per-entry summation order is fixed -> det.)
__global__ __launch_bounds__(256)
void pack_and_lists(const int* __restrict__ pieces, const int* __restrict__ kings,
                    unsigned long long* __restrict__ mask,
                    int* __restrict__ cnt, int* __restrict__ list,
                    int nwords, int nent)
{
    const int gtid = blockIdx.x * 256 + threadIdx.x;
    const int gw = blockIdx.x * 4 + (threadIdx.x >> 6);
    const int lane = threadIdx.x & 63;
    if (gw < nwords) {
        const int v = pieces[(size_t)gw * 64 + lane];
        const unsigned long long m = __ballot(v != 0);
        if (lane == 0) mask[gw] = m;
    }
    if (gtid < nent) {
        const int b = gtid >> 1, p = gtid & 1;
        const int kk = kings[2 * b + p];
        const int pos = atomicAdd(&cnt[kk], 1);
        if (pos < LCAP) list[kk * LCAP + pos] = gtid;
    }
}

__global__ __launch_bounds__(512)
void halfkp_mfma(const float* __restrict__ W,                 // (64,641,256)
                 const unsigned long long* __restrict__ mask, // (B,10)
                 const int* __restrict__ cnt,
                 const int* __restrict__ list,
                 float* __restrict__ partial)                 // (2,B,256)
{
    const int k  = blockIdx.x;
    const int cq = blockIdx.y;
    const int t  = threadIdx.x;
    const int wv = t >> 6, lane = t & 63;
    const int nt = wv & 3, kh = wv >> 2;    // N-tile 0..3, K-half 0..1
    const int g = lane >> 4, li = lane & 15;
    const int col = cq * 64 + nt * 16 + li;

    __shared__ int s_ent[64];
    __shared__ unsigned short s_mh[64][44];   // k-window bitmasks, 41 used
    __shared__ f32x4 s_red[4][4][64];         // 16 KB K-half reduce

    const int n_k = min(cnt[k], LCAP);
    const float* __restrict__ Wk = W + (size_t)k * SLAB_STRIDE;

    for (int mb = 0; mb < n_k; mb += 64) {
        const int nc = min(n_k - mb, 64);

        if (t < 64) s_ent[t] = (t < nc) ? list[k * LCAP + mb + t] : -1;
        __syncthreads();

        // build per-entry 16-bit k-window masks: window ks = features
        // [ks*16, ks*16+16); ks=40 holds only the always-active row 640.
        {
            const int e = t & 63, ks0 = t >> 6;
            const int id = s_ent[e];
            for (int ks = ks0; ks <= 40; ks += 8) {
                unsigned short v = 0;
                if (id >= 0) {
                    if (ks < 40) {
                        const unsigned long long mw = mask[(size_t)(id >> 1) * 10 + (ks >> 2)];
                        v = (unsigned short)(mw >> ((ks & 3) * 16));
                    } else {
                        v = 1;                               // extra row 640
                    }
                }
                s_mh[e][ks] = v;
            }
        }
        __syncthreads();

        f32x4 acc0 = {0.f,0.f,0.f,0.f}, acc1 = {0.f,0.f,0.f,0.f};
        f32x4 acc2 = {0.f,0.f,0.f,0.f}, acc3 = {0.f,0.f,0.f,0.f};

        const int ks_beg = kh ? 21 : 0;
        const int ks_end = kh ? 41 : 21;

        #pragma unroll 3
        for (int ks = ks_beg; ks < ks_end; ++ks) {
            // B-frag: B[k = ks*16 + g*4 + j][col], j=0..3; clamp rows >640
            const int f0 = ks * 16 + g * 4;
            const float w0 = Wk[(size_t)min(f0 + 0, F_DIM) * C_DIM + col];
            const float w1 = Wk[(size_t)min(f0 + 1, F_DIM) * C_DIM + col];
            const float w2 = Wk[(size_t)min(f0 + 2, F_DIM) * C_DIM + col];
            const float w3 = Wk[(size_t)min(f0 + 3, F_DIM) * C_DIM + col];
            s16x4 bfrag;
            {
                union { unsigned u[2]; s16x4 v; } bb;
                bb.u[0] = f2bf_pk(w0, w1);
                bb.u[1] = f2bf_pk(w2, w3);
                bfrag = bb.v;
            }
            // A-frags for the 4 M-tiles (entries mi*16+li), same k-window
            const s16x4 a0 = mk_a(s_mh[ 0 + li][ks], g);
            const s16x4 a1 = mk_a(s_mh[16 + li][ks], g);
            const s16x4 a2 = mk_a(s_mh[32 + li][ks], g);
            const s16x4 a3 = mk_a(s_mh[48 + li][ks], g);

            asm volatile(
                "s_nop 1\n\t"   // VALU-write -> MFMA-src hazard
                "v_mfma_f32_16x16x16_bf16 %0, %4, %8, %0\n\t"
                "v_mfma_f32_16x16x16_bf16 %1, %5, %8, %1\n\t"
                "v_mfma_f32_16x16x16_bf16 %2, %6, %8, %2\n\t"
                "v_mfma_f32_16x16x16_bf16 %3, %7, %8, %3"
                : "+v"(acc0), "+v"(acc1), "+v"(acc2), "+v"(acc3)
                : "v"(a0), "v"(a1), "v"(a2), "v"(a3), "v"(bfrag));
        }
        asm volatile("s_nop 7\n\ts_nop 7\n\ts_nop 7");  // MFMA -> VALU/LDS read

        __syncthreads();
        if (kh == 1) {
            s_red[nt][0][lane] = acc0;
            s_red[nt][1][lane] = acc1;
            s_red[nt][2][lane] = acc2;
            s_red[nt][3][lane] = acc3;
        }
        __syncthreads();
        if (kh == 0) {
            acc0 += s_red[nt][0][lane];
            acc1 += s_red[nt][1][lane];
            acc2 += s_red[nt][2][lane];
            acc3 += s_red[nt][3][lane];
            // D: reg i of lane -> row = 4*g + i (within M-tile), col = li
            #pragma unroll
            for (int i = 0; i < 4; ++i) {
                const int r0 = 4 * g + i;
                if (r0 < nc) {
                    const int id = s_ent[r0];
                    partial[(((size_t)(id & 1)) * 1024 + (id >> 1)) * C_DIM + col] = acc0[i];
                }
                const int r1 = 16 + 4 * g + i;
                if (r1 < nc) {
                    const int id = s_ent[r1];
                    partial[(((size_t)(id & 1)) * 1024 + (id >> 1)) * C_DIM + col] = acc1[i];
                }
                const int r2 = 32 + 4 * g + i;
                if (r2 < nc) {
                    const int id = s_ent[r2];
                    partial[(((size_t)(id & 1)) * 1024 + (id >> 1)) * C_DIM + col] = acc2[i];
                }
                const int r3 = 48 + 4 * g + i;
                if (r3 < nc) {
                    const int id = s_ent[r3];
                    partial[(((size_t)(id & 1)) * 1024 + (id >> 1)) * C_DIM + col] = acc3[i];
                }
            }
        }
        __syncthreads();   // protect LDS before next m-chunk
    }
}

__global__ __launch_bounds__(256)
void finalize(const float* __restrict__ partial,
              const float* __restrict__ bias,
              float* __restrict__ out)
{
    const int i = blockIdx.x * 256 + threadIdx.x;    // float4 index, B*64 total
    const float4 b4 = ((const float4*)bias)[i & 63];
    const float4 p0 = ((const float4*)partial)[i];
    const float4 p1 = ((const float4*)partial)[1024 * 64 + i];
    float4 o;
    o.x = b4.x + p0.x + p1.x;
    o.y = b4.y + p0.y + p1.y;
    o.z = b4.z + p0.z + p1.z;
    o.w = b4.w + p0.w + p1.w;
    ((float4*)out)[i] = o;
}

// ---- fallback (R3 path) if ws is too small ----
__global__ __launch_bounds__(256)
void halfkp_fallback(const int* __restrict__ pieces, const int* __restrict__ kings,
                     const float* __restrict__ W, const float* __restrict__ bias,
                     float* __restrict__ out)
{
    const int b = blockIdx.x;
    const int c = threadIdx.x;
    const int lane = c & 63;
    const int k0 = kings[2 * b + 0];
    const int k1 = kings[2 * b + 1];
    const float* W0 = W + (size_t)k0 * SLAB_STRIDE + c;
    const float* W1 = W + (size_t)k1 * SLAB_STRIDE + c;
    float acc = bias[c] + W0[640 * 256] + W1[640 * 256];
    const int* pi = pieces + (size_t)b * F_DIM;
    #pragma unroll
    for (int ch = 0; ch < 10; ++ch) {
        int v = pi[ch * 64 + lane];
        unsigned long long m = __ballot(v != 0);
        const float* b0 = W0 + ch * 64 * 256;
        const float* b1 = W1 + ch * 64 * 256;
        while (m) {
            const int f = __builtin_ctzll(m);
            m &= m - 1;
            acc += b0[f * 256] + b1[f * 256];
        }
    }
    out[(size_t)b * C_DIM + c] = acc;
}

extern "C" void kernel_launch(void* const* d_in, const int* in_sizes, int n_in,
                              void* d_out, int out_size, void* d_ws, size_t ws_size,
                              hipStream_t stream) {
    const int* pieces = (const int*)d_in[0];   // (1024, 640) int32 bools
    const int* kings  = (const int*)d_in[1];   // (1024, 2) int32
    const float* W    = (const float*)d_in[2]; // (64, 641, 256) f32
    const float* bias = (const float*)d_in[3]; // (256,) f32
    float* out        = (float*)d_out;         // (1024, 256) f32

    const int B = in_sizes[1] / 2;             // 1024
    const int nent = 2 * B;
    const int nwords = B * 10;

    if (ws_size < (size_t)WS_NEED) {
        halfkp_fallback<<<dim3(B), dim3(C_DIM), 0, stream>>>(pieces, kings, W, bias, out);
        return;
    }

    int* cnt  = (int*)((char*)d_ws + WS_CNT_OFF);
    int* list = (int*)((char*)d_ws + WS_LIST_OFF);
    unsigned long long* mask = (unsigned long long*)((char*)d_ws + WS_MASK_OFF);
    float* part = (float*)((char*)d_ws + WS_PART_OFF);

    hipMemsetAsync(cnt, 0, NKING * sizeof(int), stream);
    pack_and_lists<<<dim3((nwords + 3) / 4), dim3(256), 0, stream>>>(pieces, kings, mask, cnt, list, nwords, nent);
    halfkp_mfma<<<dim3(NKING, NCQ), dim3(512), 0, stream>>>(W, mask, cnt, list, part);
    finalize<<<dim3(B * 64 / 256), dim3(256), 0, stream>>>(part, bias, out);
}

// Round 9
// 28.788 us; speedup vs baseline: 3.5171x; 1.1962x over previous
//
#include <hip/hip_runtime.h>
#include <hip/hip_bf16.h>

// HalfKP input layer, king-grouped MFMA (K=32, wave=K-slice):
//   per king k: D = A_k (64x672 bf16 0/1) x W_k (672x256 -> bf16 on the fly)
//   out[b,c] = bias[c] + D[entry(b,0)] + D[entry(b,1)]
// B=1024, K=64, F=640(+row 640), C=256. W is (64,641,256) fp32 = 42 MB.
//
// R9 vs R8: (a) builtin mfma_f32_16x16x32_bf16 instead of asm (compiler can
// pipeline loads across windows; half the MFMA instrs); (b) wave = K-slice,
// covers ALL 4 M-tiles x 2 N-tiles -> zero A-frag duplication; (c) 32-col
// blocks: grid (64 kings, 8 quarters) = 512 blocks = 2/CU, 4 waves/SIMD;
// (d) 3-round LDS tree reduce over the 8 K-slices (fixed order, determ.).

#define F_DIM 640
#define C_DIM 256
#define SLAB_STRIDE (641 * 256)   // floats per king slab
#define NKING 64
#define LCAP 256                  // list capacity per king

// ws layout (bytes) — unchanged (proven to fit)
#define WS_CNT_OFF 0                         // 64*4
#define WS_LIST_OFF 1024                     // 64*256*4 = 64 KB
#define WS_MASK_OFF 66560                    // 1024*10*8 = 80 KB
#define WS_PART_OFF 148480                   // 2*1024*256*4 = 2 MB
#define WS_NEED (WS_PART_OFF + 2 * 1024 * 256 * 4)

typedef float  f32x4  __attribute__((ext_vector_type(4)));
typedef short  bf16x8 __attribute__((ext_vector_type(8)));

__device__ __forceinline__ unsigned f2bf_pk(float a, float b) {
    // two RNE fp32->bf16, packed low|high
    union { float f; unsigned u; } x, y;
    x.f = a; y.f = b;
    const unsigned ra = (x.u + 0x7FFFu + ((x.u >> 16) & 1u)) >> 16;
    const unsigned rb = (y.u + 0x7FFFu + ((y.u >> 16) & 1u)) >> 16;
    return (ra & 0xFFFFu) | (rb << 16);
}

__device__ __forceinline__ bf16x8 mk_a8(unsigned m32, int g) {
    // A-frag: 8 bf16 0/1 from byte g of a 32-bit window mask (k = g*8 + j)
    const unsigned by = (m32 >> (g * 8)) & 0xFFu;
    union { unsigned u[4]; bf16x8 v; } r;
    #pragma unroll
    for (int i = 0; i < 4; ++i)
        r.u[i] = (((by >> (2 * i)) & 1u) ? 0x3F80u : 0u) |
                 (((by >> (2 * i + 1)) & 1u) ? 0x3F800000u : 0u);
    return r.v;
}

// fused: piece bitmask packing + per-king list build (atomic order only picks
// which A-row an entry occupies; each entry's summation order is fixed -> det.)
__global__ __launch_bounds__(256)
void pack_and_lists(const int* __restrict__ pieces, const int* __restrict__ kings,
                    unsigned long long* __restrict__ mask,
                    int* __restrict__ cnt, int* __restrict__ list,
                    int nwords, int nent)
{
    const int gtid = blockIdx.x * 256 + threadIdx.x;
    const int gw = blockIdx.x * 4 + (threadIdx.x >> 6);
    const int lane = threadIdx.x & 63;
    if (gw < nwords) {
        const int v = pieces[(size_t)gw * 64 + lane];
        const unsigned long long m = __ballot(v != 0);
        if (lane == 0) mask[gw] = m;
    }
    if (gtid < nent) {
        const int b = gtid >> 1, p = gtid & 1;
        const int kk = kings[2 * b + p];
        const int pos = atomicAdd(&cnt[kk], 1);
        if (pos < LCAP) list[kk * LCAP + pos] = gtid;
    }
}

__global__ __launch_bounds__(512, 4)
void halfkp_mfma(const float* __restrict__ W,                 // (64,641,256)
                 const unsigned long long* __restrict__ mask, // (B,10)
                 const int* __restrict__ cnt,
                 const int* __restrict__ list,
                 float* __restrict__ partial)                 // (2,B,256)
{
    const int k  = blockIdx.x;
    const int cq = blockIdx.y;               // 0..7, 32 cols each
    const int t  = threadIdx.x;
    const int wv = t >> 6, lane = t & 63;    // wave = K-slice
    const int g = lane >> 4, li = lane & 15;
    const int c0 = cq * 32 + li;             // col of nt=0; nt=1 adds 16

    __shared__ int s_ent[64];
    __shared__ unsigned s_m32[64][21];       // per-row 32-feature window masks
    __shared__ f32x4 s_red[4][8][64];        // 32 KB reduce buffer

    const int n_k = min(cnt[k], LCAP);
    const float* __restrict__ Wk = W + (size_t)k * SLAB_STRIDE;

    for (int mb = 0; mb < n_k; mb += 64) {
        const int nc = min(n_k - mb, 64);

        if (t < 64) s_ent[t] = (t < nc) ? list[k * LCAP + mb + t] : -1;
        __syncthreads();

        // window ks covers features [ks*32, ks*32+32); ks=20: only row 640.
        for (int idx = t; idx < 64 * 21; idx += 512) {
            const int row = idx & 63, ks = idx >> 6;
            const int id = s_ent[row];
            unsigned v = 0;
            if (id >= 0) {
                if (ks < 20) {
                    const unsigned long long mw = mask[(size_t)(id >> 1) * 10 + (ks >> 1)];
                    v = (unsigned)(mw >> ((ks & 1) * 32));
                } else {
                    v = 1u;                  // always-active row 640
                }
            }
            s_m32[row][ks] = v;
        }
        __syncthreads();

        f32x4 acc[4][2];
        #pragma unroll
        for (int mt = 0; mt < 4; ++mt) {
            acc[mt][0] = (f32x4){0.f, 0.f, 0.f, 0.f};
            acc[mt][1] = (f32x4){0.f, 0.f, 0.f, 0.f};
        }

        // Wave wv handles windows {wv, wv+8, wv+16} (<21). Per window:
        // 16 B-loads (each weight element loaded once chip-wide), 8 packs,
        // 4 A-frags, 8 MFMA. No asm barriers -> compiler pipelines windows.
        #pragma unroll
        for (int i = 0; i < 3; ++i) {
            const int ks = wv + 8 * i;
            if (ks < 21) {                   // wave-uniform branch
                bf16x8 bf[2];
                #pragma unroll
                for (int nt = 0; nt < 2; ++nt) {
                    float wt[8];
                    #pragma unroll
                    for (int j = 0; j < 8; ++j) {
                        const int f = min(ks * 32 + g * 8 + j, F_DIM);
                        wt[j] = Wk[(size_t)f * C_DIM + c0 + nt * 16];
                    }
                    union { unsigned u[4]; bf16x8 v; } bb;
                    #pragma unroll
                    for (int j = 0; j < 4; ++j)
                        bb.u[j] = f2bf_pk(wt[2 * j], wt[2 * j + 1]);
                    bf[nt] = bb.v;
                }
                #pragma unroll
                for (int mt = 0; mt < 4; ++mt) {
                    const bf16x8 af = mk_a8(s_m32[mt * 16 + li][ks], g);
                    acc[mt][0] = __builtin_amdgcn_mfma_f32_16x16x32_bf16(af, bf[0], acc[mt][0], 0, 0, 0);
                    acc[mt][1] = __builtin_amdgcn_mfma_f32_16x16x32_bf16(af, bf[1], acc[mt][1], 0, 0, 0);
                }
            }
        }

        // 3-round tree reduce over K-slice waves: 8 -> 4 -> 2 -> 1.
        __syncthreads();
        if (wv >= 4) {
            #pragma unroll
            for (int mt = 0; mt < 4; ++mt) {
                s_red[wv - 4][mt * 2 + 0][lane] = acc[mt][0];
                s_red[wv - 4][mt * 2 + 1][lane] = acc[mt][1];
            }
        }
        __syncthreads();
        if (wv < 4) {
            #pragma unroll
            for (int mt = 0; mt < 4; ++mt) {
                acc[mt][0] += s_red[wv][mt * 2 + 0][lane];
                acc[mt][1] += s_red[wv][mt * 2 + 1][lane];
            }
        }
        __syncthreads();
        if (wv == 2 || wv == 3) {
            #pragma unroll
            for (int mt = 0; mt < 4; ++mt) {
                s_red[wv - 2][mt * 2 + 0][lane] = acc[mt][0];
                s_red[wv - 2][mt * 2 + 1][lane] = acc[mt][1];
            }
        }
        __syncthreads();
        if (wv < 2) {
            #pragma unroll
            for (int mt = 0; mt < 4; ++mt) {
                acc[mt][0] += s_red[wv][mt * 2 + 0][lane];
                acc[mt][1] += s_red[wv][mt * 2 + 1][lane];
            }
        }
        __syncthreads();
        if (wv == 1) {
            #pragma unroll
            for (int mt = 0; mt < 4; ++mt) {
                s_red[0][mt * 2 + 0][lane] = acc[mt][0];
                s_red[0][mt * 2 + 1][lane] = acc[mt][1];
            }
        }
        __syncthreads();
        if (wv == 0) {
            #pragma unroll
            for (int mt = 0; mt < 4; ++mt) {
                acc[mt][0] += s_red[0][mt * 2 + 0][lane];
                acc[mt][1] += s_red[0][mt * 2 + 1][lane];
            }
            // D: reg i -> row = mt*16 + 4*g + i, col = c0 (+16 for nt=1)
            #pragma unroll
            for (int mt = 0; mt < 4; ++mt) {
                #pragma unroll
                for (int i = 0; i < 4; ++i) {
                    const int row = mt * 16 + 4 * g + i;
                    if (row < nc) {
                        const int id = s_ent[row];
                        const size_t o = (((size_t)(id & 1)) * 1024 + (id >> 1)) * C_DIM;
                        partial[o + c0]      = acc[mt][0][i];
                        partial[o + c0 + 16] = acc[mt][1][i];
                    }
                }
            }
        }
        __syncthreads();   // protect LDS before next m-chunk
    }
}

__global__ __launch_bounds__(256)
void finalize(const float* __restrict__ partial,
              const float* __restrict__ bias,
              float* __restrict__ out)
{
    const int i = blockIdx.x * 256 + threadIdx.x;    // float4 index, B*64 total
    const float4 b4 = ((const float4*)bias)[i & 63];
    const float4 p0 = ((const float4*)partial)[i];
    const float4 p1 = ((const float4*)partial)[1024 * 64 + i];
    float4 o;
    o.x = b4.x + p0.x + p1.x;
    o.y = b4.y + p0.y + p1.y;
    o.z = b4.z + p0.z + p1.z;
    o.w = b4.w + p0.w + p1.w;
    ((float4*)out)[i] = o;
}

// ---- fallback (R3 path) if ws is too small ----
__global__ __launch_bounds__(256)
void halfkp_fallback(const int* __restrict__ pieces, const int* __restrict__ kings,
                     const float* __restrict__ W, const float* __restrict__ bias,
                     float* __restrict__ out)
{
    const int b = blockIdx.x;
    const int c = threadIdx.x;
    const int lane = c & 63;
    const int k0 = kings[2 * b + 0];
    const int k1 = kings[2 * b + 1];
    const float* W0 = W + (size_t)k0 * SLAB_STRIDE + c;
    const float* W1 = W + (size_t)k1 * SLAB_STRIDE + c;
    float acc = bias[c] + W0[640 * 256] + W1[640 * 256];
    const int* pi = pieces + (size_t)b * F_DIM;
    #pragma unroll
    for (int ch = 0; ch < 10; ++ch) {
        int v = pi[ch * 64 + lane];
        unsigned long long m = __ballot(v != 0);
        const float* b0 = W0 + ch * 64 * 256;
        const float* b1 = W1 + ch * 64 * 256;
        while (m) {
            const int f = __builtin_ctzll(m);
            m &= m - 1;
            acc += b0[f * 256] + b1[f * 256];
        }
    }
    out[(size_t)b * C_DIM + c] = acc;
}

extern "C" void kernel_launch(void* const* d_in, const int* in_sizes, int n_in,
                              void* d_out, int out_size, void* d_ws, size_t ws_size,
                              hipStream_t stream) {
    const int* pieces = (const int*)d_in[0];   // (1024, 640) int32 bools
    const int* kings  = (const int*)d_in[1];   // (1024, 2) int32
    const float* W    = (const float*)d_in[2]; // (64, 641, 256) f32
    const float* bias = (const float*)d_in[3]; // (256,) f32
    float* out        = (float*)d_out;         // (1024, 256) f32

    const int B = in_sizes[1] / 2;             // 1024
    const int nent = 2 * B;
    const int nwords = B * 10;

    if (ws_size < (size_t)WS_NEED) {
        halfkp_fallback<<<dim3(B), dim3(C_DIM), 0, stream>>>(pieces, kings, W, bias, out);
        return;
    }

    int* cnt  = (int*)((char*)d_ws + WS_CNT_OFF);
    int* list = (int*)((char*)d_ws + WS_LIST_OFF);
    unsigned long long* mask = (unsigned long long*)((char*)d_ws + WS_MASK_OFF);
    float* part = (float*)((char*)d_ws + WS_PART_OFF);

    hipMemsetAsync(cnt, 0, NKING * sizeof(int), stream);
    pack_and_lists<<<dim3((nwords + 3) / 4), dim3(256), 0, stream>>>(pieces, kings, mask, cnt, list, nwords, nent);
    halfkp_mfma<<<dim3(NKING, 8), dim3(512), 0, stream>>>(W, mask, cnt, list, part);
    finalize<<<dim3(B * 64 / 256), dim3(256), 0, stream>>>(part, bias, out);
}

// Round 10
// 27.432 us; speedup vs baseline: 3.6909x; 1.0494x over previous
//
#include <hip/hip_runtime.h>
#include <hip/hip_bf16.h>

// HalfKP input layer, king-grouped MFMA, reduction-free wave layout:
//   per king k: D = A_k (64x672 bf16 0/1) x W_k (672x256 -> bf16 on the fly)
//   out[b,c] = bias[c] + D[entry(b,0)] + D[entry(b,1)]
// B=1024, K=64, F=640(+row 640), C=256. W is (64,641,256) fp32 = 42 MB.
//
// R10 vs R9: (a) wave = (M-tile, N-half) owns its 16x16 output tile across
// ALL 21 k-windows -> no inter-wave LDS reduce (was 7 barriers + 32 KB),
// 2 barriers/chunk total; B-frag re-loads across the 4 M-waves are L1 hits.
// (b) per-block in-LDS list build from kings[] via chunked ballot + prefix +
// stable scatter (deterministic by entry index) -> no atomics, no memset,
// 3 dispatches total (pack_masks, halfkp_mfma, finalize).
// A/B/D lane mappings identical to R8/R9 (HW-verified: absmax 0.5).

#define F_DIM 640
#define C_DIM 256
#define SLAB_STRIDE (641 * 256)   // floats per king slab
#define NKING 64
#define LCAP 256                  // list capacity per king
#define NC_MAX 64                 // max 64-entry chunks (nent <= 4096)

// ws layout (bytes)
#define WS_MASK_OFF 0                        // 1024*10*8 = 80 KB
#define WS_PART_OFF 81920                    // 2*1024*256*4 = 2 MB
#define WS_NEED (WS_PART_OFF + 2 * 1024 * 256 * 4)

typedef float  f32x4  __attribute__((ext_vector_type(4)));
typedef short  bf16x8 __attribute__((ext_vector_type(8)));

__device__ __forceinline__ unsigned f2bf_pk(float a, float b) {
    // two RNE fp32->bf16, packed low|high
    union { float f; unsigned u; } x, y;
    x.f = a; y.f = b;
    const unsigned ra = (x.u + 0x7FFFu + ((x.u >> 16) & 1u)) >> 16;
    const unsigned rb = (y.u + 0x7FFFu + ((y.u >> 16) & 1u)) >> 16;
    return (ra & 0xFFFFu) | (rb << 16);
}

__device__ __forceinline__ bf16x8 mk_a8(unsigned m32, int g) {
    // A-frag: 8 bf16 0/1 from byte g of a 32-bit window mask (k = g*8 + j)
    const unsigned by = (m32 >> (g * 8)) & 0xFFu;
    union { unsigned u[4]; bf16x8 v; } r;
    #pragma unroll
    for (int i = 0; i < 4; ++i)
        r.u[i] = (((by >> (2 * i)) & 1u) ? 0x3F80u : 0u) |
                 (((by >> (2 * i + 1)) & 1u) ? 0x3F800000u : 0u);
    return r.v;
}

__global__ __launch_bounds__(256)
void pack_masks(const int* __restrict__ pieces,          // (B,640) int32 0/1
                unsigned long long* __restrict__ mask,   // (B,10)
                int nwords)                              // B*10
{
    const int gw = blockIdx.x * 4 + (threadIdx.x >> 6);
    const int lane = threadIdx.x & 63;
    if (gw >= nwords) return;
    const int v = pieces[(size_t)gw * 64 + lane];
    const unsigned long long m = __ballot(v != 0);
    if (lane == 0) mask[gw] = m;
}

__global__ __launch_bounds__(512, 4)
void halfkp_mfma(const float* __restrict__ W,                 // (64,641,256)
                 const unsigned long long* __restrict__ mask, // (B,10)
                 const int* __restrict__ kings,               // flat (B*2)
                 float* __restrict__ partial,                 // (2,B,256)
                 int nent)
{
    const int k  = blockIdx.x;
    const int cq = blockIdx.y;               // 0..7, 32 cols each
    const int t  = threadIdx.x;
    const int wv = t >> 6, lane = t & 63;
    const int mt = wv & 3, ntc = wv >> 2;    // M-tile 0..3, N-half 0..1
    const int li = lane & 15, g = lane >> 4;
    const int col = cq * 32 + ntc * 16 + li;

    __shared__ int s_ent[LCAP];
    __shared__ int s_cb[NC_MAX + 1];
    __shared__ unsigned s_m32[64][21];       // per-row 32-feature window masks
    __shared__ int s_nk;

    // ---- in-block list build: stable (entry-index-ordered) compaction ----
    const int NC = nent >> 6;                // 64-entry chunks; nent % 64 == 0
    const int nit = NC >> 3;                 // chunks per wave (8 waves)
    unsigned long long mm[8];
    #pragma unroll
    for (int it = 0; it < 8; ++it) {
        if (it < nit) {
            const int c = wv + (it << 3);
            const int kk = kings[(c << 6) + lane];   // kings flat == entry id
            mm[it] = __ballot(kk == k);
            if (lane == 0) s_cb[c] = (int)__popcll(mm[it]);
        }
    }
    __syncthreads();
    if (t == 0) {
        int s = 0;
        for (int c = 0; c < NC; ++c) { const int v = s_cb[c]; s_cb[c] = s; s += v; }
        s_cb[NC] = s;
        s_nk = min(s, LCAP);
    }
    __syncthreads();
    const unsigned long long lt = (1ull << lane) - 1ull;
    #pragma unroll
    for (int it = 0; it < 8; ++it) {
        if (it < nit) {
            const int c = wv + (it << 3);
            if ((mm[it] >> lane) & 1ull) {
                const int pos = s_cb[c] + (int)__popcll(mm[it] & lt);
                if (pos < LCAP) s_ent[pos] = (c << 6) + lane;
            }
        }
    }
    __syncthreads();
    const int n_k = s_nk;

    const float* __restrict__ Wk = W + (size_t)k * SLAB_STRIDE;
    const float* __restrict__ Wc = Wk + col;

    for (int mb = 0; mb < n_k; mb += 64) {
        const int nc = min(n_k - mb, 64);

        // window ks covers features [ks*32, ks*32+32); ks=20: only row 640.
        for (int idx = t; idx < 64 * 21; idx += 512) {
            const int row = idx & 63, ks = idx >> 6;
            const int id = (row < nc) ? s_ent[mb + row] : -1;
            unsigned v = 0;
            if (id >= 0) {
                if (ks < 20) {
                    const unsigned long long mw = mask[(size_t)(id >> 1) * 10 + (ks >> 1)];
                    v = (unsigned)(mw >> ((ks & 1) * 32));
                } else {
                    v = 1u;                  // always-active row 640
                }
            }
            s_m32[row][ks] = v;
        }
        __syncthreads();

        // ---- wave-private GEMM over all 21 windows; no cross-wave reduce ----
        f32x4 acc = {0.f, 0.f, 0.f, 0.f};
        #pragma unroll 3
        for (int ks = 0; ks < 21; ++ks) {
            float wt[8];
            #pragma unroll
            for (int j = 0; j < 8; ++j) {
                const int f = min(ks * 32 + g * 8 + j, F_DIM);
                wt[j] = Wc[(size_t)f * C_DIM];
            }
            union { unsigned u[4]; bf16x8 v; } bb;
            #pragma unroll
            for (int j = 0; j < 4; ++j)
                bb.u[j] = f2bf_pk(wt[2 * j], wt[2 * j + 1]);
            const bf16x8 af = mk_a8(s_m32[mt * 16 + li][ks], g);
            acc = __builtin_amdgcn_mfma_f32_16x16x32_bf16(af, bb.v, acc, 0, 0, 0);
        }

        // D: reg i -> row = mt*16 + 4*g + i, col = col (m89-verified rule)
        #pragma unroll
        for (int i = 0; i < 4; ++i) {
            const int row = mt * 16 + 4 * g + i;
            if (row < nc) {
                const int id = s_ent[mb + row];
                partial[(((size_t)(id & 1)) * 1024 + (id >> 1)) * C_DIM + col] = acc[i];
            }
        }
        __syncthreads();   // protect s_m32/s_ent before next chunk
    }
}

__global__ __launch_bounds__(256)
void finalize(const float* __restrict__ partial,
              const float* __restrict__ bias,
              float* __restrict__ out)
{
    const int i = blockIdx.x * 256 + threadIdx.x;    // float4 index, B*64 total
    const float4 b4 = ((const float4*)bias)[i & 63];
    const float4 p0 = ((const float4*)partial)[i];
    const float4 p1 = ((const float4*)partial)[1024 * 64 + i];
    float4 o;
    o.x = b4.x + p0.x + p1.x;
    o.y = b4.y + p0.y + p1.y;
    o.z = b4.z + p0.z + p1.z;
    o.w = b4.w + p0.w + p1.w;
    ((float4*)out)[i] = o;
}

// ---- fallback (R3 path) if ws is too small ----
__global__ __launch_bounds__(256)
void halfkp_fallback(const int* __restrict__ pieces, const int* __restrict__ kings,
                     const float* __restrict__ W, const float* __restrict__ bias,
                     float* __restrict__ out)
{
    const int b = blockIdx.x;
    const int c = threadIdx.x;
    const int lane = c & 63;
    const int k0 = kings[2 * b + 0];
    const int k1 = kings[2 * b + 1];
    const float* W0 = W + (size_t)k0 * SLAB_STRIDE + c;
    const float* W1 = W + (size_t)k1 * SLAB_STRIDE + c;
    float acc = bias[c] + W0[640 * 256] + W1[640 * 256];
    const int* pi = pieces + (size_t)b * F_DIM;
    #pragma unroll
    for (int ch = 0; ch < 10; ++ch) {
        int v = pi[ch * 64 + lane];
        unsigned long long m = __ballot(v != 0);
        const float* b0 = W0 + ch * 64 * 256;
        const float* b1 = W1 + ch * 64 * 256;
        while (m) {
            const int f = __builtin_ctzll(m);
            m &= m - 1;
            acc += b0[f * 256] + b1[f * 256];
        }
    }
    out[(size_t)b * C_DIM + c] = acc;
}

extern "C" void kernel_launch(void* const* d_in, const int* in_sizes, int n_in,
                              void* d_out, int out_size, void* d_ws, size_t ws_size,
                              hipStream_t stream) {
    const int* pieces = (const int*)d_in[0];   // (1024, 640) int32 bools
    const int* kings  = (const int*)d_in[1];   // (1024, 2) int32
    const float* W    = (const float*)d_in[2]; // (64, 641, 256) f32
    const float* bias = (const float*)d_in[3]; // (256,) f32
    float* out        = (float*)d_out;         // (1024, 256) f32

    const int B = in_sizes[1] / 2;             // 1024
    const int nent = 2 * B;
    const int nwords = B * 10;

    if (ws_size < (size_t)WS_NEED) {
        halfkp_fallback<<<dim3(B), dim3(C_DIM), 0, stream>>>(pieces, kings, W, bias, out);
        return;
    }

    unsigned long long* mask = (unsigned long long*)((char*)d_ws + WS_MASK_OFF);
    float* part = (float*)((char*)d_ws + WS_PART_OFF);

    pack_masks<<<dim3((nwords + 3) / 4), dim3(256), 0, stream>>>(pieces, mask, nwords);
    halfkp_mfma<<<dim3(NKING, 8), dim3(512), 0, stream>>>(W, mask, kings, part, nent);
    finalize<<<dim3(B * 64 / 256), dim3(256), 0, stream>>>(part, bias, out);
}